// Round 5
// baseline (725.648 us; speedup 1.0000x reference)
//
#include <hip/hip_runtime.h>
#include <cstdint>

#define BEPS 1e-5f

typedef __attribute__((ext_vector_type(8))) short short8;
typedef __attribute__((ext_vector_type(4))) float f32x4;

static __device__ __forceinline__ uint32_t f2bf(float f) {
    union { float f; uint32_t u; } v; v.f = f;
    return (v.u + 0x7FFFu + ((v.u >> 16) & 1u)) >> 16;   // RNE
}
static __device__ __forceinline__ uint32_t pk2(float lo, float hi) {
    return (f2bf(hi) << 16) | (f2bf(lo) & 0xFFFFu);
}

// ---------------- 1x1 conv as batched GEMM, bf16 MFMA ----------------
__global__ __launch_bounds__(256) void gemm1x1_mfma(
    const float* __restrict__ in, const float* __restrict__ w,
    const float* __restrict__ bias, float* __restrict__ out,
    int Ci, int Co, int P)
{
    const int b  = blockIdx.z;
    const int p0 = blockIdx.x * 128;
    const int c0 = blockIdx.y * 128;
    const int tid  = threadIdx.x;
    const int lane = tid & 63;
    const int wave = tid >> 6;
    const int wm = wave >> 1, wn = wave & 1;
    const int l15 = lane & 15;
    const int kg  = lane >> 4;     // 0..3

    __shared__ short sA[128][40];  // [co][k]
    __shared__ short sB[128][40];  // [p][k]  (X transposed)

    f32x4 acc[4][4] = {};

    const float* inb = in + (size_t)b * Ci * P;

    const int arow  = tid >> 1;
    const int ahalf = (tid & 1) * 16;
    const int bp    = tid & 127;
    const int bhalf = (tid >> 7) * 16;
    const bool bok  = (p0 + bp) < P;

    for (int k0 = 0; k0 < Ci; k0 += 32) {
        {
            const float* src = &w[(size_t)(c0 + arow) * Ci + k0 + ahalf];
            float4 f0 = *(const float4*)(src + 0);
            float4 f1 = *(const float4*)(src + 4);
            float4 f2 = *(const float4*)(src + 8);
            float4 f3 = *(const float4*)(src + 12);
            uint4 q0, q1;
            q0.x = pk2(f0.x, f0.y); q0.y = pk2(f0.z, f0.w);
            q0.z = pk2(f1.x, f1.y); q0.w = pk2(f1.z, f1.w);
            q1.x = pk2(f2.x, f2.y); q1.y = pk2(f2.z, f2.w);
            q1.z = pk2(f3.x, f3.y); q1.w = pk2(f3.z, f3.w);
            *(uint4*)&sA[arow][ahalf]     = q0;
            *(uint4*)&sA[arow][ahalf + 8] = q1;
        }
        {
            const float* src = &inb[(size_t)(k0 + bhalf) * P + p0 + bp];
            float fv[16];
#pragma unroll
            for (int i = 0; i < 16; ++i)
                fv[i] = bok ? src[(size_t)i * P] : 0.f;
            uint4 q0, q1;
            q0.x = pk2(fv[0], fv[1]);  q0.y = pk2(fv[2], fv[3]);
            q0.z = pk2(fv[4], fv[5]);  q0.w = pk2(fv[6], fv[7]);
            q1.x = pk2(fv[8], fv[9]);  q1.y = pk2(fv[10], fv[11]);
            q1.z = pk2(fv[12], fv[13]); q1.w = pk2(fv[14], fv[15]);
            *(uint4*)&sB[bp][bhalf]     = q0;
            *(uint4*)&sB[bp][bhalf + 8] = q1;
        }
        __syncthreads();

        short8 aF[4], bF[4];
#pragma unroll
        for (int m = 0; m < 4; ++m)
            aF[m] = *(const short8*)&sA[wm * 64 + m * 16 + l15][kg * 8];
#pragma unroll
        for (int n = 0; n < 4; ++n)
            bF[n] = *(const short8*)&sB[wn * 64 + n * 16 + l15][kg * 8];
#pragma unroll
        for (int m = 0; m < 4; ++m)
#pragma unroll
            for (int n = 0; n < 4; ++n)
                acc[m][n] = __builtin_amdgcn_mfma_f32_16x16x32_bf16(aF[m], bF[n], acc[m][n], 0, 0, 0);
        __syncthreads();
    }

    float* outb = out + (size_t)b * Co * P;
#pragma unroll
    for (int m = 0; m < 4; ++m) {
        int row = c0 + wm * 64 + m * 16 + kg * 4;
#pragma unroll
        for (int n = 0; n < 4; ++n) {
            int col = p0 + wn * 64 + n * 16 + l15;
            if (col < P) {
#pragma unroll
                for (int j = 0; j < 4; ++j)
                    outb[(size_t)(row + j) * P + col] = acc[m][n][j] + bias[row + j];
            }
        }
    }
}

// ---------------- depthwise 5x5 stride-2 + BN ----------------
__global__ __launch_bounds__(256) void dwconv_bn(
    const float* __restrict__ in, const float* __restrict__ w5,
    const float* __restrict__ cb, const float* __restrict__ g,
    const float* __restrict__ bb, const float* __restrict__ m,
    const float* __restrict__ v, float* __restrict__ out,
    int Hin, int Win, int Hout, int Wout, int stride, int total)
{
    int idx = blockIdx.x * 256 + threadIdx.x;
    if (idx >= total) return;
    int x = idx % Wout;
    int t = idx / Wout;
    int y = t % Hout;
    t /= Hout;
    int c = t & 255;
    int b = t >> 8;
    const float* ib = in + (size_t)(b * 256 + c) * Hin * Win;
    const float* wc = w5 + c * 25;
    float s = 0.f;
#pragma unroll
    for (int dy = 0; dy < 5; ++dy) {
        int iy = y * stride + dy - 2;
        if (iy < 0 || iy >= Hin) continue;
#pragma unroll
        for (int dx = 0; dx < 5; ++dx) {
            int ix = x * stride + dx - 2;
            if (ix < 0 || ix >= Win) continue;
            s = fmaf(wc[dy * 5 + dx], ib[iy * Win + ix], s);
        }
    }
    s += cb[c];
    float sc = g[c] * rsqrtf(v[c] + BEPS);
    out[idx] = (s - m[c]) * sc + bb[c];
}

// ---------------- attention via MFMA ----------------
// grid (49, 8, 16), 256 thr = 4 waves; wave handles 16 q-rows (block: 64).
// Phase 1 (transposed): S^T[key][q] = K·Q^T  (A=K-frag, B=Q-frag)
// softmax per q-row: row is lane-local-ish (col=l15=q); reduce over kg via shfl_xor 16/32
// Phase 2 (transposed): O^T[d][q] = V^T·P^T  (A=Vt-frag, B=P-frag) -> coalesced gf write
__global__ __launch_bounds__(256) void attn_mfma(
    const float* __restrict__ qloc,   // [B][256][3136]
    const float* __restrict__ kvbuf,  // [B][512][196]
    float* __restrict__ gf)           // [B][256][3136]
{
    const int b  = blockIdx.z;
    const int h  = blockIdx.y;
    const int p0 = blockIdx.x * 64;
    const int tid  = threadIdx.x;
    const int lane = tid & 63;
    const int w    = tid >> 6;
    const int l15  = lane & 15;
    const int kg   = lane >> 4;

    __shared__ __align__(16) short sK[208][40];      // [key][d], keys >=196 zero
    __shared__ __align__(16) short sVt[32][248];     // [d][key], keys >=196 zero
    __shared__ __align__(16) short sP[4][16][248];   // per wave: [q][key]; Q staging aliases this

    short* sQf = &sP[0][0][0];                       // alias: [64][40] bf16 [qrow][d]

    const float* kp = kvbuf + ((size_t)b * 512 + h * 32) * 196;
    const float* vp = kvbuf + ((size_t)b * 512 + 256 + h * 32) * 196;
    const float* qp = qloc + ((size_t)b * 256 + h * 32) * 3136 + p0;

    // stage K (transpose): sK[key][d] = kp[d*196+key]
    for (int idx = tid; idx < 208 * 32; idx += 256) {
        int d = idx / 208, key = idx - d * 208;
        float val = (key < 196) ? kp[d * 196 + key] : 0.f;
        sK[key][d] = (short)f2bf(val);
    }
    // stage Vt (direct): sVt[d][key] = vp[d*196+key], packed pairs
    for (int idx = tid; idx < 32 * 124; idx += 256) {
        int d = idx / 124, kp2 = idx - d * 124;
        int key = kp2 * 2;
        float v0 = (key < 196) ? vp[d * 196 + key] : 0.f;
        float v1 = (key + 1 < 196) ? vp[d * 196 + key + 1] : 0.f;
        *(uint32_t*)&sVt[d][key] = pk2(v0, v1);
    }
    // stage Q (transpose) into alias: sQf[r*40+d] = qp[d*3136+r]
    for (int idx = tid; idx < 64 * 32; idx += 256) {
        int d = idx / 64, r = idx - d * 64;
        sQf[r * 40 + d] = (short)f2bf(qp[(size_t)d * 3136 + r]);
    }
    __syncthreads();

    // read own Q B-frag, then barrier before sP region is overwritten
    short8 bQ = *(const short8*)&sQf[(w * 16 + l15) * 40 + kg * 8];
    __syncthreads();

    // zero own wave's sP pad columns [208..247]
#pragma unroll
    for (int i = 0; i < 5; ++i)
        *(uint32_t*)&sP[w][l15][208 + (kg * 5 + i) * 2] = 0u;

    // scores: S^T tiles, 13 MFMAs
    f32x4 sAcc[13];
#pragma unroll
    for (int t = 0; t < 13; ++t) {
        short8 aK = *(const short8*)&sK[t * 16 + l15][kg * 8];
        f32x4 z = {0.f, 0.f, 0.f, 0.f};
        sAcc[t] = __builtin_amdgcn_mfma_f32_16x16x32_bf16(aK, bQ, z, 0, 0, 0);
    }

    // softmax (no max-subtraction: |s*scal| small, validated in fp32 version)
    const float scal = 0.17677669529663687f;
    float rsum = 0.f;
#pragma unroll
    for (int t = 0; t < 13; ++t) {
#pragma unroll
        for (int j = 0; j < 4; ++j) {
            int key = t * 16 + kg * 4 + j;
            float e = (key < 196) ? __expf(sAcc[t][j] * scal) : 0.f;
            sAcc[t][j] = e;
            rsum += e;
        }
    }
    rsum += __shfl_xor(rsum, 16);
    rsum += __shfl_xor(rsum, 32);
    float inv = 1.f / rsum;

    // write P (bf16, normalized): sP[w][q=l15][key]
#pragma unroll
    for (int t = 0; t < 13; ++t) {
        uint32_t w0 = pk2(sAcc[t][0] * inv, sAcc[t][1] * inv);
        uint32_t w1 = pk2(sAcc[t][2] * inv, sAcc[t][3] * inv);
        *(uint32_t*)&sP[w][l15][t * 16 + kg * 4 + 0] = w0;
        *(uint32_t*)&sP[w][l15][t * 16 + kg * 4 + 2] = w1;
    }
    __syncthreads();   // cross-lane P visibility

    // PV: O^T[d][q], 7 K-chunks x 2 d-tiles
    f32x4 oAcc[2] = {};
#pragma unroll
    for (int c = 0; c < 7; ++c) {
        short8 bP = *(const short8*)&sP[w][l15][c * 32 + kg * 8];
#pragma unroll
        for (int mt = 0; mt < 2; ++mt) {
            short8 aV = *(const short8*)&sVt[mt * 16 + l15][c * 32 + kg * 8];
            oAcc[mt] = __builtin_amdgcn_mfma_f32_16x16x32_bf16(aV, bP, oAcc[mt], 0, 0, 0);
        }
    }

    // write O^T: col(l15)=q, row(kg*4+j)=d -> gf[b][h*32+d][p0 + w*16 + l15]
    float* op = gf + ((size_t)b * 256 + h * 32) * 3136 + p0 + w * 16;
#pragma unroll
    for (int mt = 0; mt < 2; ++mt) {
#pragma unroll
        for (int j = 0; j < 4; ++j) {
            int d = mt * 16 + kg * 4 + j;
            op[(size_t)d * 3136 + l15] = oAcc[mt][j];
        }
    }
}

// ---------------- local dwconv 5x5 s1 + silu + global gating ----------------
__global__ __launch_bounds__(256) void gate_kernel(
    const float* __restrict__ ql, const float* __restrict__ w5,
    const float* __restrict__ cb, const float* __restrict__ gfb,
    float* __restrict__ t_out, int total)
{
    int idx = blockIdx.x * 256 + threadIdx.x;
    if (idx >= total) return;
    int x = idx % 56;
    int t = idx / 56;
    int y = t % 56;
    t /= 56;
    int c = t & 255;
    int b = t >> 8;
    const float* ib = ql + (size_t)(b * 256 + c) * 3136;
    const float* wc = w5 + c * 25;
    float s = 0.f;
#pragma unroll
    for (int dy = 0; dy < 5; ++dy) {
        int iy = y + dy - 2;
        if (iy < 0 || iy >= 56) continue;
#pragma unroll
        for (int dx = 0; dx < 5; ++dx) {
            int ix = x + dx - 2;
            if (ix < 0 || ix >= 56) continue;
            s = fmaf(wc[dy * 5 + dx], ib[iy * 56 + ix], s);
        }
    }
    s += cb[c];
    float gv = gfb[idx];
    float sl = s / (1.f + __expf(-s));        // silu(lf)
    float sg = 1.f / (1.f + __expf(-gv));     // sigmoid(gf)
    t_out[idx] = sl * sg * gv;
}

extern "C" void kernel_launch(void* const* d_in, const int* in_sizes, int n_in,
                              void* d_out, int out_size, void* d_ws, size_t ws_size,
                              hipStream_t stream)
{
    const float* x     = (const float*)d_in[0];
    const float* q_w   = (const float*)d_in[1];
    const float* q_b   = (const float*)d_in[2];
    const float* kv_w  = (const float*)d_in[3];
    const float* kv_b  = (const float*)d_in[4];
    const float* p0_w  = (const float*)d_in[5];
    const float* p0_b  = (const float*)d_in[6];
    const float* bn0_g = (const float*)d_in[7];
    const float* bn0_b = (const float*)d_in[8];
    const float* bn0_m = (const float*)d_in[9];
    const float* bn0_v = (const float*)d_in[10];
    const float* pl0_w = (const float*)d_in[11];
    const float* pl0_b = (const float*)d_in[12];
    const float* p1_w  = (const float*)d_in[13];
    const float* p1_b  = (const float*)d_in[14];
    const float* bn1_g = (const float*)d_in[15];
    const float* bn1_b = (const float*)d_in[16];
    const float* bn1_m = (const float*)d_in[17];
    const float* bn1_v = (const float*)d_in[18];
    const float* loc_w = (const float*)d_in[19];
    const float* loc_b = (const float*)d_in[20];
    const float* mix_w = (const float*)d_in[21];
    const float* mix_b = (const float*)d_in[22];

    float* qlocal = (float*)d_out;           // q_local lives in d_out; overwritten by final mix
    float* ws  = (float*)d_ws;
    float* gf  = ws;                          // 12845056 floats
    float* tb  = ws + 12845056;               // 12845056 floats (p-chain sublets this region)
    float* p0  = tb;                          // 3211264
    float* pl0 = tb + 3211264;                // 3211264
    float* p1  = tb + 6422528;                // 802816
    float* kv  = tb + 7225344;                // 1605632

    // 1. q projection (1x1)
    gemm1x1_mfma<<<dim3(25, 2, 16), 256, 0, stream>>>(x, q_w, q_b, qlocal, 256, 256, 3136);
    // 2. dwconv s2 + BN0
    dwconv_bn<<<dim3(12544), 256, 0, stream>>>(x, p0_w, p0_b, bn0_g, bn0_b, bn0_m, bn0_v,
                                               p0, 56, 56, 28, 28, 2, 3211264);
    // 3. pl0 (1x1)
    gemm1x1_mfma<<<dim3(7, 2, 16), 256, 0, stream>>>(p0, pl0_w, pl0_b, pl0, 256, 256, 784);
    // 4. dwconv s2 + BN1
    dwconv_bn<<<dim3(3136), 256, 0, stream>>>(pl0, p1_w, p1_b, bn1_g, bn1_b, bn1_m, bn1_v,
                                              p1, 28, 28, 14, 14, 2, 802816);
    // 5. kv projection (1x1, Co=512)
    gemm1x1_mfma<<<dim3(2, 4, 16), 256, 0, stream>>>(p1, kv_w, kv_b, kv, 256, 512, 196);
    // 6. attention (MFMA) -> global_feat
    attn_mfma<<<dim3(49, 8, 16), 256, 0, stream>>>(qlocal, kv, gf);
    // 7. local dwconv + silu + gating -> t
    gate_kernel<<<dim3(50176), 256, 0, stream>>>(qlocal, loc_w, loc_b, gf, tb, 12845056);
    // 8. mix (1x1) -> d_out
    gemm1x1_mfma<<<dim3(25, 2, 16), 256, 0, stream>>>(tb, mix_w, mix_b, qlocal, 256, 256, 3136);
}

// Round 6
// 552.213 us; speedup vs baseline: 1.3141x; 1.3141x over previous
//
#include <hip/hip_runtime.h>
#include <cstdint>

#define BEPS 1e-5f

typedef __attribute__((ext_vector_type(8))) short short8;
typedef __attribute__((ext_vector_type(4))) float f32x4;

static __device__ __forceinline__ uint32_t f2bf(float f) {
    union { float f; uint32_t u; } v; v.f = f;
    return (v.u + 0x7FFFu + ((v.u >> 16) & 1u)) >> 16;   // RNE
}
static __device__ __forceinline__ uint32_t pk2(float lo, float hi) {
    return (f2bf(hi) << 16) | (f2bf(lo) & 0xFFFFu);
}

// ---------------- 1x1 conv as batched GEMM, bf16 MFMA ----------------
__global__ __launch_bounds__(256) void gemm1x1_mfma(
    const float* __restrict__ in, const float* __restrict__ w,
    const float* __restrict__ bias, float* __restrict__ out,
    int Ci, int Co, int P)
{
    const int b  = blockIdx.z;
    const int p0 = blockIdx.x * 128;
    const int c0 = blockIdx.y * 128;
    const int tid  = threadIdx.x;
    const int lane = tid & 63;
    const int wave = tid >> 6;
    const int wm = wave >> 1, wn = wave & 1;
    const int l15 = lane & 15;
    const int kg  = lane >> 4;     // 0..3

    __shared__ short sA[128][40];  // [co][k]
    __shared__ short sB[128][40];  // [p][k]  (X transposed)

    f32x4 acc[4][4] = {};

    const float* inb = in + (size_t)b * Ci * P;

    const int arow  = tid >> 1;
    const int ahalf = (tid & 1) * 16;
    const int bp    = tid & 127;
    const int bhalf = (tid >> 7) * 16;
    const bool bok  = (p0 + bp) < P;

    for (int k0 = 0; k0 < Ci; k0 += 32) {
        {
            const float* src = &w[(size_t)(c0 + arow) * Ci + k0 + ahalf];
            float4 f0 = *(const float4*)(src + 0);
            float4 f1 = *(const float4*)(src + 4);
            float4 f2 = *(const float4*)(src + 8);
            float4 f3 = *(const float4*)(src + 12);
            uint4 q0, q1;
            q0.x = pk2(f0.x, f0.y); q0.y = pk2(f0.z, f0.w);
            q0.z = pk2(f1.x, f1.y); q0.w = pk2(f1.z, f1.w);
            q1.x = pk2(f2.x, f2.y); q1.y = pk2(f2.z, f2.w);
            q1.z = pk2(f3.x, f3.y); q1.w = pk2(f3.z, f3.w);
            *(uint4*)&sA[arow][ahalf]     = q0;
            *(uint4*)&sA[arow][ahalf + 8] = q1;
        }
        {
            const float* src = &inb[(size_t)(k0 + bhalf) * P + p0 + bp];
            float fv[16];
#pragma unroll
            for (int i = 0; i < 16; ++i)
                fv[i] = bok ? src[(size_t)i * P] : 0.f;
            uint4 q0, q1;
            q0.x = pk2(fv[0], fv[1]);  q0.y = pk2(fv[2], fv[3]);
            q0.z = pk2(fv[4], fv[5]);  q0.w = pk2(fv[6], fv[7]);
            q1.x = pk2(fv[8], fv[9]);  q1.y = pk2(fv[10], fv[11]);
            q1.z = pk2(fv[12], fv[13]); q1.w = pk2(fv[14], fv[15]);
            *(uint4*)&sB[bp][bhalf]     = q0;
            *(uint4*)&sB[bp][bhalf + 8] = q1;
        }
        __syncthreads();

        short8 aF[4], bF[4];
#pragma unroll
        for (int m = 0; m < 4; ++m)
            aF[m] = *(const short8*)&sA[wm * 64 + m * 16 + l15][kg * 8];
#pragma unroll
        for (int n = 0; n < 4; ++n)
            bF[n] = *(const short8*)&sB[wn * 64 + n * 16 + l15][kg * 8];
#pragma unroll
        for (int m = 0; m < 4; ++m)
#pragma unroll
            for (int n = 0; n < 4; ++n)
                acc[m][n] = __builtin_amdgcn_mfma_f32_16x16x32_bf16(aF[m], bF[n], acc[m][n], 0, 0, 0);
        __syncthreads();
    }

    float* outb = out + (size_t)b * Co * P;
#pragma unroll
    for (int m = 0; m < 4; ++m) {
        int row = c0 + wm * 64 + m * 16 + kg * 4;
#pragma unroll
        for (int n = 0; n < 4; ++n) {
            int col = p0 + wn * 64 + n * 16 + l15;
            if (col < P) {
#pragma unroll
                for (int j = 0; j < 4; ++j)
                    outb[(size_t)(row + j) * P + col] = acc[m][n][j] + bias[row + j];
            }
        }
    }
}

// ---------------- depthwise 5x5 stride-2 + BN ----------------
__global__ __launch_bounds__(256) void dwconv_bn(
    const float* __restrict__ in, const float* __restrict__ w5,
    const float* __restrict__ cb, const float* __restrict__ g,
    const float* __restrict__ bb, const float* __restrict__ m,
    const float* __restrict__ v, float* __restrict__ out,
    int Hin, int Win, int Hout, int Wout, int stride, int total)
{
    int idx = blockIdx.x * 256 + threadIdx.x;
    if (idx >= total) return;
    int x = idx % Wout;
    int t = idx / Wout;
    int y = t % Hout;
    t /= Hout;
    int c = t & 255;
    int b = t >> 8;
    const float* ib = in + (size_t)(b * 256 + c) * Hin * Win;
    const float* wc = w5 + c * 25;
    float s = 0.f;
#pragma unroll
    for (int dy = 0; dy < 5; ++dy) {
        int iy = y * stride + dy - 2;
        if (iy < 0 || iy >= Hin) continue;
#pragma unroll
        for (int dx = 0; dx < 5; ++dx) {
            int ix = x * stride + dx - 2;
            if (ix < 0 || ix >= Win) continue;
            s = fmaf(wc[dy * 5 + dx], ib[iy * Win + ix], s);
        }
    }
    s += cb[c];
    float sc = g[c] * rsqrtf(v[c] + BEPS);
    out[idx] = (s - m[c]) * sc + bb[c];
}

// ---------------- attention via MFMA, v2 ----------------
// grid (7, 8, 16), 256 thr = 4 waves; wave handles 7 q-tiles of 16 (block: 448 q).
// K fragments in VGPRs (loaded once per wave from L2-resident kv).
// V in LDS (coalesced f4 reads, conflict-free dword writes, stride 216).
// P wave-private in LDS (no block barrier after initial V stage).
__global__ __launch_bounds__(256, 3) void attn_mfma2(
    const float* __restrict__ qloc,   // [B][256][3136]
    const float* __restrict__ kvbuf,  // [B][512][196]
    float* __restrict__ gf)           // [B][256][3136]
{
    const int b  = blockIdx.z;
    const int h  = blockIdx.y;
    const int p0 = blockIdx.x * 448;
    const int tid  = threadIdx.x;
    const int lane = tid & 63;
    const int w    = tid >> 6;
    const int l15  = lane & 15;
    const int kg   = lane >> 4;

    __shared__ __align__(16) short sV[32][216];      // [d][key], keys >=196 zero
    __shared__ __align__(16) short sP[4][16][216];   // per wave: [q][key]

    const float* kp = kvbuf + ((size_t)b * 512 + h * 32) * 196;
    const float* vp = kvbuf + ((size_t)b * 512 + 256 + h * 32) * 196;
    const float* qp = qloc + ((size_t)b * 256 + h * 32) * 3136 + p0;
    float* op = gf + ((size_t)b * 256 + h * 32) * 3136 + p0;

    // ---- stage V: 32 rows x 52 float4 (cols >=196 zero); coalesced reads,
    // dword LDS writes within-row (conflict-free)
    for (int idx = tid; idx < 32 * 52; idx += 256) {
        int d = idx / 52, c4 = idx - d * 52;
        float4 vv;
        if (c4 < 49) vv = *(const float4*)&vp[d * 196 + c4 * 4];
        else         vv = make_float4(0.f, 0.f, 0.f, 0.f);
        uint2 u2 = make_uint2(pk2(vv.x, vv.y), pk2(vv.z, vv.w));
        *(uint2*)&sV[d][c4 * 4] = u2;
    }

    // ---- K fragments into VGPRs: aK[t] lane(l15,kg) = K[t*16+l15][kg*8+j]
    short8 aK[13];
#pragma unroll
    for (int t = 0; t < 13; ++t) {
        int key = t * 16 + l15;
        float kvv[8];
#pragma unroll
        for (int j = 0; j < 8; ++j)
            kvv[j] = (key < 196) ? kp[(size_t)(kg * 8 + j) * 196 + key] : 0.f;
        union { short8 s; uint32_t u[4]; } pk_;
        pk_.u[0] = pk2(kvv[0], kvv[1]);
        pk_.u[1] = pk2(kvv[2], kvv[3]);
        pk_.u[2] = pk2(kvv[4], kvv[5]);
        pk_.u[3] = pk2(kvv[6], kvv[7]);
        aK[t] = pk_.s;
    }
    __syncthreads();   // V visible to all waves

    const float scal = 0.17677669529663687f;  // 32^-0.5
    const short8 zz = {0, 0, 0, 0, 0, 0, 0, 0};

    // ---- Q prefetch for tile 0
    float qv[8];
#pragma unroll
    for (int j = 0; j < 8; ++j)
        qv[j] = qp[(size_t)(kg * 8 + j) * 3136 + (w * 7) * 16 + l15];

#pragma unroll
    for (int i = 0; i < 7; ++i) {
        const int qbase = (w * 7 + i) * 16;

        // pack current Q B-frag
        union { short8 s; uint32_t u[4]; } bq;
        bq.u[0] = pk2(qv[0], qv[1]);
        bq.u[1] = pk2(qv[2], qv[3]);
        bq.u[2] = pk2(qv[4], qv[5]);
        bq.u[3] = pk2(qv[6], qv[7]);

        // prefetch next tile's Q
        if (i < 6) {
#pragma unroll
            for (int j = 0; j < 8; ++j)
                qv[j] = qp[(size_t)(kg * 8 + j) * 3136 + (w * 7 + i + 1) * 16 + l15];
        }

        // QK^T: S^T tiles (col=q=l15, row=key=kg*4+j), 13 independent MFMAs
        f32x4 sAcc[13];
#pragma unroll
        for (int t = 0; t < 13; ++t) {
            f32x4 z = {0.f, 0.f, 0.f, 0.f};
            sAcc[t] = __builtin_amdgcn_mfma_f32_16x16x32_bf16(aK[t], bq.s, z, 0, 0, 0);
        }

        // softmax over keys (no max-subtraction: scores are O(0.2), validated)
        float rsum = 0.f;
#pragma unroll
        for (int t = 0; t < 13; ++t) {
#pragma unroll
            for (int j = 0; j < 4; ++j) {
                int key = t * 16 + kg * 4 + j;
                float e = (key < 196) ? __expf(sAcc[t][j] * scal) : 0.f;
                sAcc[t][j] = e;
                rsum += e;
            }
        }
        rsum += __shfl_xor(rsum, 16);
        rsum += __shfl_xor(rsum, 32);
        float inv = 1.f / rsum;

        // write P (bf16 normalized) into wave-private LDS
#pragma unroll
        for (int t = 0; t < 13; ++t) {
            uint64_t v64 = (uint64_t)pk2(sAcc[t][2] * inv, sAcc[t][3] * inv) << 32
                         | (uint64_t)pk2(sAcc[t][0] * inv, sAcc[t][1] * inv);
            *(uint64_t*)&sP[w][l15][t * 16 + kg * 4] = v64;
        }
        // same-wave DS ordering: ensure P writes complete before reads
        asm volatile("s_waitcnt lgkmcnt(0)" ::: "memory");

        // PV: O^T[d][q], 7 key-chunks x 2 d-tiles
        f32x4 oAcc[2] = {};
#pragma unroll
        for (int c = 0; c < 7; ++c) {
            int col = c * 32 + kg * 8;
            bool valid = (c < 6) || (kg < 2);       // cols >207 are out of pad
            int cs = valid ? col : 0;
            short8 bP  = *(const short8*)&sP[w][l15][cs];
            short8 aV0 = *(const short8*)&sV[l15][cs];
            short8 aV1 = *(const short8*)&sV[16 + l15][cs];
            if (!valid) bP = zz;
            oAcc[0] = __builtin_amdgcn_mfma_f32_16x16x32_bf16(aV0, bP, oAcc[0], 0, 0, 0);
            oAcc[1] = __builtin_amdgcn_mfma_f32_16x16x32_bf16(aV1, bP, oAcc[1], 0, 0, 0);
        }

        // store O^T: d = mt*16+kg*4+j, q = qbase+l15 (16-lane coalesced)
        float* ob = op + qbase + l15;
#pragma unroll
        for (int mt = 0; mt < 2; ++mt)
#pragma unroll
            for (int j = 0; j < 4; ++j)
                ob[(size_t)(mt * 16 + kg * 4 + j) * 3136] = oAcc[mt][j];
    }
}

// ---------------- local dwconv 5x5 s1 + silu + global gating ----------------
__global__ __launch_bounds__(256) void gate_kernel(
    const float* __restrict__ ql, const float* __restrict__ w5,
    const float* __restrict__ cb, const float* __restrict__ gfb,
    float* __restrict__ t_out, int total)
{
    int idx = blockIdx.x * 256 + threadIdx.x;
    if (idx >= total) return;
    int x = idx % 56;
    int t = idx / 56;
    int y = t % 56;
    t /= 56;
    int c = t & 255;
    int b = t >> 8;
    const float* ib = ql + (size_t)(b * 256 + c) * 3136;
    const float* wc = w5 + c * 25;
    float s = 0.f;
#pragma unroll
    for (int dy = 0; dy < 5; ++dy) {
        int iy = y + dy - 2;
        if (iy < 0 || iy >= 56) continue;
#pragma unroll
        for (int dx = 0; dx < 5; ++dx) {
            int ix = x + dx - 2;
            if (ix < 0 || ix >= 56) continue;
            s = fmaf(wc[dy * 5 + dx], ib[iy * 56 + ix], s);
        }
    }
    s += cb[c];
    float gv = gfb[idx];
    float sl = s / (1.f + __expf(-s));        // silu(lf)
    float sg = 1.f / (1.f + __expf(-gv));     // sigmoid(gf)
    t_out[idx] = sl * sg * gv;
}

extern "C" void kernel_launch(void* const* d_in, const int* in_sizes, int n_in,
                              void* d_out, int out_size, void* d_ws, size_t ws_size,
                              hipStream_t stream)
{
    const float* x     = (const float*)d_in[0];
    const float* q_w   = (const float*)d_in[1];
    const float* q_b   = (const float*)d_in[2];
    const float* kv_w  = (const float*)d_in[3];
    const float* kv_b  = (const float*)d_in[4];
    const float* p0_w  = (const float*)d_in[5];
    const float* p0_b  = (const float*)d_in[6];
    const float* bn0_g = (const float*)d_in[7];
    const float* bn0_b = (const float*)d_in[8];
    const float* bn0_m = (const float*)d_in[9];
    const float* bn0_v = (const float*)d_in[10];
    const float* pl0_w = (const float*)d_in[11];
    const float* pl0_b = (const float*)d_in[12];
    const float* p1_w  = (const float*)d_in[13];
    const float* p1_b  = (const float*)d_in[14];
    const float* bn1_g = (const float*)d_in[15];
    const float* bn1_b = (const float*)d_in[16];
    const float* bn1_m = (const float*)d_in[17];
    const float* bn1_v = (const float*)d_in[18];
    const float* loc_w = (const float*)d_in[19];
    const float* loc_b = (const float*)d_in[20];
    const float* mix_w = (const float*)d_in[21];
    const float* mix_b = (const float*)d_in[22];

    float* qlocal = (float*)d_out;           // q_local lives in d_out; overwritten by final mix
    float* ws  = (float*)d_ws;
    float* gf  = ws;                          // 12845056 floats
    float* tb  = ws + 12845056;               // 12845056 floats (p-chain sublets this region)
    float* p0  = tb;                          // 3211264
    float* pl0 = tb + 3211264;                // 3211264
    float* p1  = tb + 6422528;                // 802816
    float* kv  = tb + 7225344;                // 1605632

    // 1. q projection (1x1)
    gemm1x1_mfma<<<dim3(25, 2, 16), 256, 0, stream>>>(x, q_w, q_b, qlocal, 256, 256, 3136);
    // 2. dwconv s2 + BN0
    dwconv_bn<<<dim3(12544), 256, 0, stream>>>(x, p0_w, p0_b, bn0_g, bn0_b, bn0_m, bn0_v,
                                               p0, 56, 56, 28, 28, 2, 3211264);
    // 3. pl0 (1x1)
    gemm1x1_mfma<<<dim3(7, 2, 16), 256, 0, stream>>>(p0, pl0_w, pl0_b, pl0, 256, 256, 784);
    // 4. dwconv s2 + BN1
    dwconv_bn<<<dim3(3136), 256, 0, stream>>>(pl0, p1_w, p1_b, bn1_g, bn1_b, bn1_m, bn1_v,
                                              p1, 28, 28, 14, 14, 2, 802816);
    // 5. kv projection (1x1, Co=512)
    gemm1x1_mfma<<<dim3(2, 4, 16), 256, 0, stream>>>(p1, kv_w, kv_b, kv, 256, 512, 196);
    // 6. attention (MFMA v2) -> global_feat
    attn_mfma2<<<dim3(7, 8, 16), 256, 0, stream>>>(qlocal, kv, gf);
    // 7. local dwconv + silu + gating -> t
    gate_kernel<<<dim3(50176), 256, 0, stream>>>(qlocal, loc_w, loc_b, gf, tb, 12845056);
    // 8. mix (1x1) -> d_out
    gemm1x1_mfma<<<dim3(25, 2, 16), 256, 0, stream>>>(tb, mix_w, mix_b, qlocal, 256, 256, 3136);
}

// Round 8
// 410.233 us; speedup vs baseline: 1.7689x; 1.3461x over previous
//
#include <hip/hip_runtime.h>
#include <cstdint>

#define BEPS 1e-5f

typedef __attribute__((ext_vector_type(8))) short short8;
typedef __attribute__((ext_vector_type(4))) float f32x4;

static __device__ __forceinline__ uint32_t f2bf(float f) {
    union { float f; uint32_t u; } v; v.f = f;
    return (v.u + 0x7FFFu + ((v.u >> 16) & 1u)) >> 16;   // RNE
}
static __device__ __forceinline__ uint32_t pk2(float lo, float hi) {
    return (f2bf(hi) << 16) | (f2bf(lo) & 0xFFFFu);
}

// ---------------- 1x1 conv as batched GEMM, bf16 MFMA ----------------
__global__ __launch_bounds__(256) void gemm1x1_mfma(
    const float* __restrict__ in, const float* __restrict__ w,
    const float* __restrict__ bias, float* __restrict__ out,
    int Ci, int Co, int P)
{
    const int b  = blockIdx.z;
    const int p0 = blockIdx.x * 128;
    const int c0 = blockIdx.y * 128;
    const int tid  = threadIdx.x;
    const int lane = tid & 63;
    const int wave = tid >> 6;
    const int wm = wave >> 1, wn = wave & 1;
    const int l15 = lane & 15;
    const int kg  = lane >> 4;     // 0..3

    __shared__ short sA[128][40];  // [co][k]
    __shared__ short sB[128][40];  // [p][k]  (X transposed)

    f32x4 acc[4][4] = {};

    const float* inb = in + (size_t)b * Ci * P;

    const int arow  = tid >> 1;
    const int ahalf = (tid & 1) * 16;
    const int bp    = tid & 127;
    const int bhalf = (tid >> 7) * 16;
    const bool bok  = (p0 + bp) < P;

    for (int k0 = 0; k0 < Ci; k0 += 32) {
        {
            const float* src = &w[(size_t)(c0 + arow) * Ci + k0 + ahalf];
            float4 f0 = *(const float4*)(src + 0);
            float4 f1 = *(const float4*)(src + 4);
            float4 f2 = *(const float4*)(src + 8);
            float4 f3 = *(const float4*)(src + 12);
            uint4 q0, q1;
            q0.x = pk2(f0.x, f0.y); q0.y = pk2(f0.z, f0.w);
            q0.z = pk2(f1.x, f1.y); q0.w = pk2(f1.z, f1.w);
            q1.x = pk2(f2.x, f2.y); q1.y = pk2(f2.z, f2.w);
            q1.z = pk2(f3.x, f3.y); q1.w = pk2(f3.z, f3.w);
            *(uint4*)&sA[arow][ahalf]     = q0;
            *(uint4*)&sA[arow][ahalf + 8] = q1;
        }
        {
            const float* src = &inb[(size_t)(k0 + bhalf) * P + p0 + bp];
            float fv[16];
#pragma unroll
            for (int i = 0; i < 16; ++i)
                fv[i] = bok ? src[(size_t)i * P] : 0.f;
            uint4 q0, q1;
            q0.x = pk2(fv[0], fv[1]);  q0.y = pk2(fv[2], fv[3]);
            q0.z = pk2(fv[4], fv[5]);  q0.w = pk2(fv[6], fv[7]);
            q1.x = pk2(fv[8], fv[9]);  q1.y = pk2(fv[10], fv[11]);
            q1.z = pk2(fv[12], fv[13]); q1.w = pk2(fv[14], fv[15]);
            *(uint4*)&sB[bp][bhalf]     = q0;
            *(uint4*)&sB[bp][bhalf + 8] = q1;
        }
        __syncthreads();

        short8 aF[4], bF[4];
#pragma unroll
        for (int m = 0; m < 4; ++m)
            aF[m] = *(const short8*)&sA[wm * 64 + m * 16 + l15][kg * 8];
#pragma unroll
        for (int n = 0; n < 4; ++n)
            bF[n] = *(const short8*)&sB[wn * 64 + n * 16 + l15][kg * 8];
#pragma unroll
        for (int m = 0; m < 4; ++m)
#pragma unroll
            for (int n = 0; n < 4; ++n)
                acc[m][n] = __builtin_amdgcn_mfma_f32_16x16x32_bf16(aF[m], bF[n], acc[m][n], 0, 0, 0);
        __syncthreads();
    }

    float* outb = out + (size_t)b * Co * P;
#pragma unroll
    for (int m = 0; m < 4; ++m) {
        int row = c0 + wm * 64 + m * 16 + kg * 4;
#pragma unroll
        for (int n = 0; n < 4; ++n) {
            int col = p0 + wn * 64 + n * 16 + l15;
            if (col < P) {
#pragma unroll
                for (int j = 0; j < 4; ++j)
                    outb[(size_t)(row + j) * P + col] = acc[m][n][j] + bias[row + j];
            }
        }
    }
}

// ---------------- depthwise 5x5 stride-2 + BN ----------------
__global__ __launch_bounds__(256) void dwconv_bn(
    const float* __restrict__ in, const float* __restrict__ w5,
    const float* __restrict__ cb, const float* __restrict__ g,
    const float* __restrict__ bb, const float* __restrict__ m,
    const float* __restrict__ v, float* __restrict__ out,
    int Hin, int Win, int Hout, int Wout, int stride, int total)
{
    int idx = blockIdx.x * 256 + threadIdx.x;
    if (idx >= total) return;
    int x = idx % Wout;
    int t = idx / Wout;
    int y = t % Hout;
    t /= Hout;
    int c = t & 255;
    int b = t >> 8;
    const float* ib = in + (size_t)(b * 256 + c) * Hin * Win;
    const float* wc = w5 + c * 25;
    float s = 0.f;
#pragma unroll
    for (int dy = 0; dy < 5; ++dy) {
        int iy = y * stride + dy - 2;
        if (iy < 0 || iy >= Hin) continue;
#pragma unroll
        for (int dx = 0; dx < 5; ++dx) {
            int ix = x * stride + dx - 2;
            if (ix < 0 || ix >= Win) continue;
            s = fmaf(wc[dy * 5 + dx], ib[iy * Win + ix], s);
        }
    }
    s += cb[c];
    float sc = g[c] * rsqrtf(v[c] + BEPS);
    out[idx] = (s - m[c]) * sc + bb[c];
}

// ---------------- attention via MFMA, v2 ----------------
__global__ __launch_bounds__(256, 3) void attn_mfma2(
    const float* __restrict__ qloc,   // [B][256][3136]
    const float* __restrict__ kvbuf,  // [B][512][196]
    float* __restrict__ gf)           // [B][256][3136]
{
    const int b  = blockIdx.z;
    const int h  = blockIdx.y;
    const int p0 = blockIdx.x * 448;
    const int tid  = threadIdx.x;
    const int lane = tid & 63;
    const int w    = tid >> 6;
    const int l15  = lane & 15;
    const int kg   = lane >> 4;

    __shared__ __align__(16) short sV[32][216];      // [d][key], keys >=196 zero
    __shared__ __align__(16) short sP[4][16][216];   // per wave: [q][key]

    const float* kp = kvbuf + ((size_t)b * 512 + h * 32) * 196;
    const float* vp = kvbuf + ((size_t)b * 512 + 256 + h * 32) * 196;
    const float* qp = qloc + ((size_t)b * 256 + h * 32) * 3136 + p0;
    float* op = gf + ((size_t)b * 256 + h * 32) * 3136 + p0;

    for (int idx = tid; idx < 32 * 52; idx += 256) {
        int d = idx / 52, c4 = idx - d * 52;
        float4 vv;
        if (c4 < 49) vv = *(const float4*)&vp[d * 196 + c4 * 4];
        else         vv = make_float4(0.f, 0.f, 0.f, 0.f);
        uint2 u2 = make_uint2(pk2(vv.x, vv.y), pk2(vv.z, vv.w));
        *(uint2*)&sV[d][c4 * 4] = u2;
    }

    short8 aK[13];
#pragma unroll
    for (int t = 0; t < 13; ++t) {
        int key = t * 16 + l15;
        float kvv[8];
#pragma unroll
        for (int j = 0; j < 8; ++j)
            kvv[j] = (key < 196) ? kp[(size_t)(kg * 8 + j) * 196 + key] : 0.f;
        union { short8 s; uint32_t u[4]; } pk_;
        pk_.u[0] = pk2(kvv[0], kvv[1]);
        pk_.u[1] = pk2(kvv[2], kvv[3]);
        pk_.u[2] = pk2(kvv[4], kvv[5]);
        pk_.u[3] = pk2(kvv[6], kvv[7]);
        aK[t] = pk_.s;
    }
    __syncthreads();   // V visible to all waves

    const float scal = 0.17677669529663687f;  // 32^-0.5
    const short8 zz = {0, 0, 0, 0, 0, 0, 0, 0};

    float qv[8];
#pragma unroll
    for (int j = 0; j < 8; ++j)
        qv[j] = qp[(size_t)(kg * 8 + j) * 3136 + (w * 7) * 16 + l15];

#pragma unroll
    for (int i = 0; i < 7; ++i) {
        const int qbase = (w * 7 + i) * 16;

        union { short8 s; uint32_t u[4]; } bq;
        bq.u[0] = pk2(qv[0], qv[1]);
        bq.u[1] = pk2(qv[2], qv[3]);
        bq.u[2] = pk2(qv[4], qv[5]);
        bq.u[3] = pk2(qv[6], qv[7]);

        if (i < 6) {
#pragma unroll
            for (int j = 0; j < 8; ++j)
                qv[j] = qp[(size_t)(kg * 8 + j) * 3136 + (w * 7 + i + 1) * 16 + l15];
        }

        f32x4 sAcc[13];
#pragma unroll
        for (int t = 0; t < 13; ++t) {
            f32x4 z = {0.f, 0.f, 0.f, 0.f};
            sAcc[t] = __builtin_amdgcn_mfma_f32_16x16x32_bf16(aK[t], bq.s, z, 0, 0, 0);
        }

        float rsum = 0.f;
#pragma unroll
        for (int t = 0; t < 13; ++t) {
#pragma unroll
            for (int j = 0; j < 4; ++j) {
                int key = t * 16 + kg * 4 + j;
                float e = (key < 196) ? __expf(sAcc[t][j] * scal) : 0.f;
                sAcc[t][j] = e;
                rsum += e;
            }
        }
        rsum += __shfl_xor(rsum, 16);
        rsum += __shfl_xor(rsum, 32);
        float inv = 1.f / rsum;

#pragma unroll
        for (int t = 0; t < 13; ++t) {
            uint64_t v64 = (uint64_t)pk2(sAcc[t][2] * inv, sAcc[t][3] * inv) << 32
                         | (uint64_t)pk2(sAcc[t][0] * inv, sAcc[t][1] * inv);
            *(uint64_t*)&sP[w][l15][t * 16 + kg * 4] = v64;
        }
        asm volatile("s_waitcnt lgkmcnt(0)" ::: "memory");

        f32x4 oAcc[2] = {};
#pragma unroll
        for (int c = 0; c < 7; ++c) {
            int col = c * 32 + kg * 8;
            bool valid = (c < 6) || (kg < 2);       // cols >207 are out of pad
            int cs = valid ? col : 0;
            short8 bP  = *(const short8*)&sP[w][l15][cs];
            short8 aV0 = *(const short8*)&sV[l15][cs];
            short8 aV1 = *(const short8*)&sV[16 + l15][cs];
            if (!valid) bP = zz;
            oAcc[0] = __builtin_amdgcn_mfma_f32_16x16x32_bf16(aV0, bP, oAcc[0], 0, 0, 0);
            oAcc[1] = __builtin_amdgcn_mfma_f32_16x16x32_bf16(aV1, bP, oAcc[1], 0, 0, 0);
        }

        float* ob = op + qbase + l15;
#pragma unroll
        for (int mt = 0; mt < 2; ++mt)
#pragma unroll
            for (int j = 0; j < 4; ++j)
                ob[(size_t)(mt * 16 + kg * 4 + j) * 3136] = oAcc[mt][j];
    }
}

// ---------------- gate v2: LDS-tiled dwconv 5x5 + silu + gating ----------------
// one block per (b,c) plane; tile [60][64] with 2-col pads; 4 outputs/thread/iter
__global__ __launch_bounds__(256) void gate_kernel2(
    const float* __restrict__ ql, const float* __restrict__ w5,
    const float* __restrict__ cb, const float* __restrict__ gfb,
    float* __restrict__ t_out)
{
    const int bc  = blockIdx.x;          // b*256 + c
    const int c   = bc & 255;
    const int tid = threadIdx.x;

    __shared__ float tile[60][64];       // rows: y -2..57; data cols 2..57

    const float* ib = ql + (size_t)bc * 3136;

    // stage plane + halo: 60 rows x 14 float4, coalesced
    for (int idx = tid; idx < 840; idx += 256) {
        int r = idx / 14, c4 = idx - r * 14;
        int y = r - 2;
        float4 v;
        if (y >= 0 && y < 56) v = *(const float4*)&ib[y * 56 + c4 * 4];
        else                  v = make_float4(0.f, 0.f, 0.f, 0.f);
        float2* dst = (float2*)&tile[r][2 + c4 * 4];   // 8B-aligned
        dst[0] = make_float2(v.x, v.y);
        dst[1] = make_float2(v.z, v.w);
    }
    // zero pad columns 0,1,58,59
    if (tid < 240) {
        int r = tid >> 2, pc = tid & 3;
        tile[r][(pc < 2) ? pc : 56 + pc] = 0.f;
    }

    // block-uniform weights -> scalar regs
    float wv[25];
    const float* wc = w5 + c * 25;
#pragma unroll
    for (int i = 0; i < 25; ++i) wv[i] = wc[i];
    const float bias = cb[c];

    __syncthreads();

    const float* gb = gfb + (size_t)bc * 3136;
    float* tb = t_out + (size_t)bc * 3136;

    for (int g = tid; g < 784; g += 256) {
        int y = g / 14, x4 = (g - y * 14) * 4;
        float acc[4] = {bias, bias, bias, bias};
#pragma unroll
        for (int dy = 0; dy < 5; ++dy) {
            float v[8];
            *(float4*)&v[0] = *(const float4*)&tile[y + dy][x4];
            *(float4*)&v[4] = *(const float4*)&tile[y + dy][x4 + 4];
#pragma unroll
            for (int o = 0; o < 4; ++o)
#pragma unroll
                for (int dx = 0; dx < 5; ++dx)
                    acc[o] = fmaf(wv[dy * 5 + dx], v[o + dx], acc[o]);
        }
        float4 gv = *(const float4*)&gb[y * 56 + x4];
        float gvv[4] = {gv.x, gv.y, gv.z, gv.w};
        float ov[4];
#pragma unroll
        for (int o = 0; o < 4; ++o) {
            float s  = acc[o];
            float sl = s / (1.f + __expf(-s));       // silu(lf)
            float sg = 1.f / (1.f + __expf(-gvv[o])); // sigmoid(gf)
            ov[o] = sl * sg * gvv[o];
        }
        *(float4*)&tb[y * 56 + x4] = make_float4(ov[0], ov[1], ov[2], ov[3]);
    }
}

extern "C" void kernel_launch(void* const* d_in, const int* in_sizes, int n_in,
                              void* d_out, int out_size, void* d_ws, size_t ws_size,
                              hipStream_t stream)
{
    const float* x     = (const float*)d_in[0];
    const float* q_w   = (const float*)d_in[1];
    const float* q_b   = (const float*)d_in[2];
    const float* kv_w  = (const float*)d_in[3];
    const float* kv_b  = (const float*)d_in[4];
    const float* p0_w  = (const float*)d_in[5];
    const float* p0_b  = (const float*)d_in[6];
    const float* bn0_g = (const float*)d_in[7];
    const float* bn0_b = (const float*)d_in[8];
    const float* bn0_m = (const float*)d_in[9];
    const float* bn0_v = (const float*)d_in[10];
    const float* pl0_w = (const float*)d_in[11];
    const float* pl0_b = (const float*)d_in[12];
    const float* p1_w  = (const float*)d_in[13];
    const float* p1_b  = (const float*)d_in[14];
    const float* bn1_g = (const float*)d_in[15];
    const float* bn1_b = (const float*)d_in[16];
    const float* bn1_m = (const float*)d_in[17];
    const float* bn1_v = (const float*)d_in[18];
    const float* loc_w = (const float*)d_in[19];
    const float* loc_b = (const float*)d_in[20];
    const float* mix_w = (const float*)d_in[21];
    const float* mix_b = (const float*)d_in[22];

    float* qlocal = (float*)d_out;           // q_local lives in d_out; overwritten by final mix
    float* ws  = (float*)d_ws;
    float* gf  = ws;                          // 12845056 floats
    float* tb  = ws + 12845056;               // 12845056 floats (p-chain sublets this region)
    float* p0  = tb;                          // 3211264
    float* pl0 = tb + 3211264;                // 3211264
    float* p1  = tb + 6422528;                // 802816
    float* kv  = tb + 7225344;                // 1605632

    // 1. q projection (1x1)
    gemm1x1_mfma<<<dim3(25, 2, 16), 256, 0, stream>>>(x, q_w, q_b, qlocal, 256, 256, 3136);
    // 2. dwconv s2 + BN0
    dwconv_bn<<<dim3(12544), 256, 0, stream>>>(x, p0_w, p0_b, bn0_g, bn0_b, bn0_m, bn0_v,
                                               p0, 56, 56, 28, 28, 2, 3211264);
    // 3. pl0 (1x1)
    gemm1x1_mfma<<<dim3(7, 2, 16), 256, 0, stream>>>(p0, pl0_w, pl0_b, pl0, 256, 256, 784);
    // 4. dwconv s2 + BN1
    dwconv_bn<<<dim3(3136), 256, 0, stream>>>(pl0, p1_w, p1_b, bn1_g, bn1_b, bn1_m, bn1_v,
                                              p1, 28, 28, 14, 14, 2, 802816);
    // 5. kv projection (1x1, Co=512)
    gemm1x1_mfma<<<dim3(2, 4, 16), 256, 0, stream>>>(p1, kv_w, kv_b, kv, 256, 512, 196);
    // 6. attention (MFMA v2) -> global_feat
    attn_mfma2<<<dim3(7, 8, 16), 256, 0, stream>>>(qlocal, kv, gf);
    // 7. local dwconv + silu + gating -> t  (LDS-tiled)
    gate_kernel2<<<dim3(4096), 256, 0, stream>>>(qlocal, loc_w, loc_b, gf, tb);
    // 8. mix (1x1) -> d_out
    gemm1x1_mfma<<<dim3(25, 2, 16), 256, 0, stream>>>(tb, mix_w, mix_b, qlocal, 256, 256, 3136);
}